// Round 2
// baseline (963.252 us; speedup 1.0000x reference)
//
#include <hip/hip_runtime.h>
#include <cstddef>

// Problem constants: B=64, C=256, H*W=1024, N=B*HW=65536, n_embed=1024.
static constexpr int OUT_DIFF = 16777216;   // diff region (also used as "flat" staging)
static constexpr int OUT_IDX  = 33554432;
static constexpr int OUT_ENEW = 33619968;
static constexpr int OUT_CSN  = 33882112;
static constexpr int OUT_EAVG = 33883136;

// ---------------------------------------------------------------- K1: prep
// blocks 0..1023: embedT[k][c] = embed[c][k]; esq[k] = sum_c embed[c][k]^2
//   (sequential ascending c, squares rounded first -> matches np axis-0 reduce)
// block 1024: n = 0.99*sum(cluster_size) + 0.01*65536  (2% slack on consumers)
__global__ __launch_bounds__(256) void k_prep(const float* __restrict__ embed,
                                              const float* __restrict__ cs_in,
                                              float* __restrict__ embedT,
                                              float* __restrict__ esq,
                                              float* __restrict__ nval) {
  const int wg = blockIdx.x;
  const int tid = threadIdx.x;
  if (wg < 1024) {
    __shared__ float col[256];
    const int k = wg;
    float v = embed[(size_t)tid * 1024 + k];
    col[tid] = v;
    embedT[(size_t)k * 256 + tid] = v;
    __syncthreads();
    if (tid == 0) {
#pragma clang fp contract(off)
      float s = 0.f;
      for (int c = 0; c < 256; ++c) { float u = col[c]; s += u * u; }
      esq[k] = s;
    }
  } else {
    __shared__ float red[256];
    float v = cs_in[tid] + cs_in[tid + 256] + cs_in[tid + 512] + cs_in[tid + 768];
    red[tid] = v;
    __syncthreads();
    for (int off = 128; off > 0; off >>= 1) {
      if (tid < off) red[tid] += red[tid + off];
      __syncthreads();
    }
    if (tid == 0) nval[0] = 0.99f * red[0] + 0.01f * 65536.0f;
  }
}

// ------------------------------------------------------------- K2: flatten
// input (B,C,HW) -> flat (N,C) via LDS tile; flat staged in the diff region.
__global__ __launch_bounds__(256) void k_flatten(const float* __restrict__ inp,
                                                 float* __restrict__ flat) {
  const int tid = threadIdx.x;
  const int b = blockIdx.x >> 4;
  const int hw0 = (blockIdx.x & 15) * 64;
  __shared__ float t[64 * 257];
#pragma unroll
  for (int r = 0; r < 16; ++r) {
    int i = tid + r * 256;
    int c = i >> 4, l = i & 15;
    float4 v = *(const float4*)(inp + (size_t)b * 262144 + (size_t)c * 1024 + hw0 + l * 4);
    t[(l * 4 + 0) * 257 + c] = v.x;
    t[(l * 4 + 1) * 257 + c] = v.y;
    t[(l * 4 + 2) * 257 + c] = v.z;
    t[(l * 4 + 3) * 257 + c] = v.w;
  }
  __syncthreads();
#pragma unroll
  for (int r = 0; r < 16; ++r) {
    int i = tid + r * 256;
    int hw = i >> 6, c4 = (i & 63) * 4;
    float4 o;
    o.x = t[hw * 257 + c4 + 0];
    o.y = t[hw * 257 + c4 + 1];
    o.z = t[hw * 257 + c4 + 2];
    o.w = t[hw * 257 + c4 + 3];
    *(float4*)(flat + ((size_t)(b * 1024 + hw0 + hw)) * 256 + c4) = o;
  }
}

// -------------------------------------------------------------- K3: argmin
// 512 WGs x 256 thr. WG = 128 points x all 1024 codes (4 chunks of 256).
// Thread tile: 8 points x 16 codes (codes swizzled k = k0 + g*64 + tc*4 + jj
// so e-fragment ds_read_b128 are conflict-free). Dist accumulation is a
// single-accumulator ascending-c fmaf chain -> bitwise matches BLAS sgemm.
__global__ __launch_bounds__(256) void k_argmin(const float* __restrict__ inp,
                                                const float* __restrict__ embed,
                                                const float* __restrict__ esq,
                                                int* __restrict__ idx_out,
                                                float* __restrict__ idxf_out) {
  __shared__ float xs[8][128];     // [cc][point]
  __shared__ float es[8][256];     // [cc][code]
  __shared__ float xsqh[2][128];
  __shared__ float xsq_s[128];

  const int tid = threadIdx.x;
  const int n0 = blockIdx.x * 128;
  const int b = n0 >> 10;
  const int hw0 = n0 & 1023;
  const float* xbase = inp + (size_t)b * 262144 + hw0;  // x[p][c] = xbase[c*1024+p]

  // ---- xsq: replicate numpy pairwise sum over 256 (= pw(128) + pw(128))
  {
#pragma clang fp contract(off)
    const int p = tid & 127, h = tid >> 7;
    const float* xb = xbase + (size_t)(h * 128) * 1024 + p;
    float r[8];
#pragma unroll
    for (int j = 0; j < 8; ++j) { float v = xb[(size_t)j * 1024]; r[j] = v * v; }
#pragma unroll 1
    for (int blk = 1; blk < 16; ++blk) {
#pragma unroll
      for (int j = 0; j < 8; ++j) { float v = xb[(size_t)(blk * 8 + j) * 1024]; r[j] += v * v; }
    }
    xsqh[h][p] = ((r[0] + r[1]) + (r[2] + r[3])) + ((r[4] + r[5]) + (r[6] + r[7]));
    __syncthreads();
    if (tid < 128) xsq_s[tid] = xsqh[0][tid] + xsqh[1][tid];
    // visibility guaranteed by first staging barrier below
  }

  const int tc = tid & 15, tr = tid >> 4;
  float bestv[8];
  int besti[8];
#pragma unroll
  for (int p = 0; p < 8; ++p) { bestv[p] = 3.0e38f; besti[p] = 0; }

#pragma unroll 1
  for (int kt = 0; kt < 4; ++kt) {
    const int k0 = kt * 256;
    float acc[8][16];
#pragma unroll
    for (int p = 0; p < 8; ++p)
#pragma unroll
      for (int j = 0; j < 16; ++j) acc[p][j] = 0.f;

#pragma unroll 1
    for (int cs = 0; cs < 32; ++cs) {
      const int c0 = cs * 8;
      {
        int cc = tid >> 5, l = tid & 31;
        *(float4*)&xs[cc][l * 4] =
            *(const float4*)(xbase + (size_t)(c0 + cc) * 1024 + l * 4);
      }
#pragma unroll
      for (int j = 0; j < 2; ++j) {
        int i = tid + j * 256;
        int cc = i >> 6, l = i & 63;
        *(float4*)&es[cc][l * 4] =
            *(const float4*)(embed + (size_t)(c0 + cc) * 1024 + k0 + l * 4);
      }
      __syncthreads();
#pragma unroll
      for (int cc = 0; cc < 8; ++cc) {
        alignas(16) float xr[8];
        alignas(16) float er[16];
        *(float4*)&xr[0] = *(float4*)&xs[cc][tr * 8];
        *(float4*)&xr[4] = *(float4*)&xs[cc][tr * 8 + 4];
#pragma unroll
        for (int g = 0; g < 4; ++g)
          *(float4*)&er[g * 4] = *(float4*)&es[cc][g * 64 + tc * 4];
#pragma unroll
        for (int p = 0; p < 8; ++p)
#pragma unroll
          for (int j = 0; j < 16; ++j)
            acc[p][j] = __builtin_fmaf(xr[p], er[j], acc[p][j]);
      }
      __syncthreads();
    }
    // epilogue: dist = (xsq - 2*dot) + esq, exact reference rounding order
    alignas(16) float esqr[16];
#pragma unroll
    for (int g = 0; g < 4; ++g)
      *(float4*)&esqr[g * 4] = *(const float4*)(esq + k0 + g * 64 + tc * 4);
#pragma unroll
    for (int p = 0; p < 8; ++p) {
      float xq = xsq_s[tr * 8 + p];
#pragma unroll
      for (int g = 0; g < 4; ++g)
#pragma unroll
        for (int jj = 0; jj < 4; ++jj) {
          int j = g * 4 + jj;
          float d = (xq - 2.0f * acc[p][j]) + esqr[j];
          int k = k0 + g * 64 + tc * 4 + jj;
          if (d < bestv[p]) { bestv[p] = d; besti[p] = k; }
        }
    }
  }
  // reduce (v, idx) lexicographically over the 16 tc lanes
#pragma unroll
  for (int p = 0; p < 8; ++p) {
    float v = bestv[p];
    int ii = besti[p];
#pragma unroll
    for (int off = 1; off < 16; off <<= 1) {
      float ov = __shfl_xor(v, off);
      int oi = __shfl_xor(ii, off);
      if (ov < v || (ov == v && oi < ii)) { v = ov; ii = oi; }
    }
    if (tc == 0) {
      int n = n0 + tr * 8 + p;
      idx_out[n] = ii;
      idxf_out[n] = (float)ii;
    }
  }
}

// -------------------------------------------------------------- K4: update
// One WG per code k: scan indices, compact matches to LDS, coalesced float4
// row sums from flat; then EMA outputs. No global atomics.
__global__ __launch_bounds__(256) void k_update(const int* __restrict__ idx,
                                                const float* __restrict__ flat,
                                                const float* __restrict__ cs_in,
                                                const float* __restrict__ eavg,
                                                const float* __restrict__ nval,
                                                float* __restrict__ csn_out,
                                                float* __restrict__ eavgn_out,
                                                float* __restrict__ enew_out) {
  const int k = blockIdx.x;
  const int tid = threadIdx.x;
  const int w = tid >> 6, lane = tid & 63;
  __shared__ int list_s[8192];
  __shared__ int lcnt;
  __shared__ float sums_s[4][256];
  float4 acc = make_float4(0.f, 0.f, 0.f, 0.f);
  int total = 0;
#pragma unroll 1
  for (int seg = 0; seg < 65536; seg += 8192) {
    __syncthreads();
    if (tid == 0) lcnt = 0;
    __syncthreads();
#pragma unroll 1
    for (int r = 0; r < 32; ++r) {
      int i = seg + r * 256 + tid;
      if (idx[i] == k) { int pos = atomicAdd(&lcnt, 1); list_s[pos] = i; }
    }
    __syncthreads();
    int cnt = lcnt;
    total += cnt;
#pragma unroll 1
    for (int e = w; e < cnt; e += 4) {
      const float* row = flat + (size_t)list_s[e] * 256;
      float4 x4 = *(const float4*)(row + lane * 4);
      acc.x += x4.x; acc.y += x4.y; acc.z += x4.z; acc.w += x4.w;
    }
  }
  __syncthreads();
  *(float4*)&sums_s[w][lane * 4] = acc;
  __syncthreads();
  {
    const int c = tid;
    float s = ((sums_s[0][c] + sums_s[1][c]) + sums_s[2][c]) + sums_s[3][c];
    float cntf = (float)total;
    float csn = cs_in[k] * 0.99f + cntf * 0.01f;
    float nv = nval[0];
    float csk = (csn + 1e-5f) / (nv + 0.01024f) * nv;
    float ean = eavg[(size_t)c * 1024 + k] * 0.99f + s * 0.01f;
    eavgn_out[(size_t)c * 1024 + k] = ean;
    enew_out[(size_t)c * 1024 + k] = ean / csk;
    if (tid == 0) csn_out[k] = csn;
  }
}

// --------------------------------------------------------------- K5: diffq
// diff = q - x (in place over flat), quantize = x + (q - x) bit-exactly,
// transposed back to (B,C,HW) via LDS.
__global__ __launch_bounds__(256) void k_diffq(const int* __restrict__ idx,
                                               const float* __restrict__ embedT,
                                               float* __restrict__ flat_diff,
                                               float* __restrict__ q_out) {
  const int tid = threadIdx.x;
  const int b = blockIdx.x >> 4;
  const int hw0 = (blockIdx.x & 15) * 64;
  const int n0 = b * 1024 + hw0;
  __shared__ float t[64 * 257];
#pragma unroll
  for (int r = 0; r < 16; ++r) {
    int i = tid + r * 256;
    int hw = i >> 6, c4 = (i & 63) * 4;
    int n = n0 + hw;
    int kk = idx[n];
    float4 q = *(const float4*)(embedT + (size_t)kk * 256 + c4);
    float4 x = *(const float4*)(flat_diff + (size_t)n * 256 + c4);
    float4 d;
    d.x = q.x - x.x; d.y = q.y - x.y; d.z = q.z - x.z; d.w = q.w - x.w;
    *(float4*)(flat_diff + (size_t)n * 256 + c4) = d;
    t[hw * 257 + c4 + 0] = x.x + d.x;
    t[hw * 257 + c4 + 1] = x.y + d.y;
    t[hw * 257 + c4 + 2] = x.z + d.z;
    t[hw * 257 + c4 + 3] = x.w + d.w;
  }
  __syncthreads();
#pragma unroll
  for (int r = 0; r < 16; ++r) {
    int i = tid + r * 256;
    int c = i >> 4, l = i & 15;
    float4 o;
    o.x = t[(l * 4 + 0) * 257 + c];
    o.y = t[(l * 4 + 1) * 257 + c];
    o.z = t[(l * 4 + 2) * 257 + c];
    o.w = t[(l * 4 + 3) * 257 + c];
    *(float4*)(q_out + (size_t)b * 262144 + (size_t)c * 1024 + hw0 + l * 4) = o;
  }
}

// ----------------------------------------------------------------- launch
extern "C" void kernel_launch(void* const* d_in, const int* in_sizes, int n_in,
                              void* d_out, int out_size, void* d_ws, size_t ws_size,
                              hipStream_t stream) {
  (void)in_sizes; (void)n_in; (void)out_size; (void)ws_size;
  const float* inp   = (const float*)d_in[0];
  const float* embed = (const float*)d_in[1];
  const float* cs_in = (const float*)d_in[2];
  const float* eavg  = (const float*)d_in[3];
  float* out = (float*)d_out;

  int*   idx_ws = (int*)d_ws;
  float* wsf    = (float*)d_ws;
  float* embedT = wsf + 65536;       // 1 MB
  float* esq    = embedT + 262144;   // 4 KB
  float* nval   = esq + 1024;        // 4 B   (total ws use ~1.3 MB)

  hipLaunchKernelGGL(k_prep,    dim3(1025), dim3(256), 0, stream, embed, cs_in, embedT, esq, nval);
  hipLaunchKernelGGL(k_flatten, dim3(1024), dim3(256), 0, stream, inp, out + OUT_DIFF);
  hipLaunchKernelGGL(k_argmin,  dim3(512),  dim3(256), 0, stream, inp, embed, esq, idx_ws, out + OUT_IDX);
  hipLaunchKernelGGL(k_update,  dim3(1024), dim3(256), 0, stream, idx_ws, out + OUT_DIFF, cs_in, eavg, nval,
                     out + OUT_CSN, out + OUT_EAVG, out + OUT_ENEW);
  hipLaunchKernelGGL(k_diffq,   dim3(1024), dim3(256), 0, stream, idx_ws, embedT, out + OUT_DIFF, out);
}